// Round 5
// baseline (1233.048 us; speedup 1.0000x reference)
//
#include <hip/hip_runtime.h>
#include <math.h>

#define N_NODES 40000
#define N_EDGES 640000
#define NT0 16

typedef short short8 __attribute__((ext_vector_type(8)));
typedef unsigned short ushort8v __attribute__((ext_vector_type(8)));
typedef unsigned short ushort4v __attribute__((ext_vector_type(4)));
typedef float fragC __attribute__((ext_vector_type(4)));

__device__ __forceinline__ float softplus_f(float x) {
    return x > 15.f ? x : __logf(1.f + __expf(x));
}
__device__ __forceinline__ float sigmoid_f(float x) {
    return 1.f / (1.f + __expf(-x));
}
__device__ __forceinline__ short f2bf(float f) {
    unsigned u = __float_as_uint(f);
    u += 0x7FFF + ((u >> 16) & 1);   // round-to-nearest-even
    return (short)(u >> 16);
}
__device__ __forceinline__ float bf2f(unsigned short u) {
    return __uint_as_float(((unsigned)u) << 16);
}

// ---------- bf16 weight prep ----------
__global__ void k_weights(const float* __restrict__ Wa, const float* __restrict__ W2g,
                          const float* __restrict__ W2, short* __restrict__ WaTb,
                          short* __restrict__ W2gTb, short* __restrict__ W2Tb) {
    int idx = blockIdx.x * blockDim.x + threadIdx.x;
    int stride = gridDim.x * blockDim.x;
    for (int i = idx; i < 256 * 64; i += stride) {
        int c = i >> 6, k = i & 63;
        WaTb[i] = f2bf(Wa[(64 + k) * 256 + c]);
    }
    for (int i = idx; i < 64 * 64; i += stride) {
        int c = i >> 6, k = i & 63;
        W2gTb[i] = f2bf(W2g[k * 64 + c]);
        W2Tb[i]  = f2bf(W2[k * 64 + c]);
    }
}

// ---------- K0: node precompute into transposed/packed tables ----------
__global__ __launch_bounds__(256) void k_node_pre(const float* __restrict__ X,
                                                  const float* __restrict__ Wg,
                                                  const float* __restrict__ Wm,
                                                  const float* __restrict__ Wa,
                                                  short* __restrict__ nodeAxaT,
                                                  short* __restrict__ nodeGT,
                                                  float* __restrict__ nodeDT) {
    __shared__ float xs[NT0 * 64];
    int t = threadIdx.x;
    int n0 = blockIdx.x * NT0;
    ((float4*)xs)[t] = ((const float4*)(X + (size_t)n0 * 64))[t];
    __syncthreads();
    for (int c = t; c < 640; c += 256) {
        const float* wptr;
        int ld;
        if (c < 192)      { wptr = Wg + (c >> 6) * 64 * 64 + (c & 63); ld = 64; }
        else if (c < 384) { wptr = Wm + ((c - 192) >> 6) * 64 * 64 + (c & 63); ld = 64; }
        else              { wptr = Wa + (c - 384); ld = 256; }
        float acc[NT0];
#pragma unroll
        for (int n = 0; n < NT0; n++) acc[n] = 0.f;
        for (int kc = 0; kc < 16; kc++) {
            float w0 = wptr[(4 * kc + 0) * ld];
            float w1 = wptr[(4 * kc + 1) * ld];
            float w2 = wptr[(4 * kc + 2) * ld];
            float w3 = wptr[(4 * kc + 3) * ld];
#pragma unroll
            for (int n = 0; n < NT0; n++) {
                float4 x = ((float4*)xs)[n * 16 + kc];
                acc[n] += x.x * w0 + x.y * w1 + x.z * w2 + x.w * w3;
            }
        }
#pragma unroll
        for (int n = 0; n < NT0; n++) {
            float v = acc[n];
            size_t nn = (size_t)(n0 + n);
            if (c < 64) {
                nodeGT[nn * 256 + (c & 15) * 4 + (c >> 4)] = f2bf(v);              // Ag1
            } else if (c < 128) {
                int d = c - 64;  nodeGT[nn * 256 + 64 + (d & 15) * 4 + (d >> 4)] = f2bf(v);   // Ag2
            } else if (c < 192) {
                int d = c - 128; nodeDT[nn * 128 + (d & 15) * 4 + (d >> 4)] = v;              // Ag3
            } else if (c < 256) {
                int d = c - 192; nodeGT[nn * 256 + 128 + (d & 15) * 4 + (d >> 4)] = f2bf(v);  // Am1
            } else if (c < 320) {
                int d = c - 256; nodeGT[nn * 256 + 192 + (d & 15) * 4 + (d >> 4)] = f2bf(v);  // Am2
            } else if (c < 384) {
                int d = c - 320; nodeDT[nn * 128 + 64 + (d & 15) * 4 + (d >> 4)] = v;         // Am3
            } else {
                int co = c - 384; nodeAxaT[nn * 256 + (co & 15) * 16 + (co >> 4)] = f2bf(v);  // Axa
            }
        }
    }
}

// ---------- K1: MFMA ea@Wa2, alpha, segment sum (Round-4 proven form) ----------
__global__ __launch_bounds__(256) void k_alpha(
    const float* __restrict__ ea, const int* __restrict__ src, const int* __restrict__ tgt,
    const unsigned short* __restrict__ nodeAxaT, const short* __restrict__ WaTb,
    const float* __restrict__ att, const float* __restrict__ gamma,
    const float* __restrict__ beta,
    float* __restrict__ alphaBuf, float* __restrict__ segSum) {
    __shared__ short ldsW[256 * 72];   // padded row stride 72 shorts (144B)
    __shared__ float attS[512];
    int t = threadIdx.x;
    {
        const float4* s4 = (const float4*)(WaTb + t * 64);
        float4* d4 = (float4*)(ldsW + t * 72);
#pragma unroll
        for (int k = 0; k < 8; k++) d4[k] = s4[k];
        attS[t] = att[(t >> 6) * 128 + (t & 63)];
        attS[256 + t] = att[(t >> 6) * 128 + 64 + (t & 63)];
    }
    __syncthreads();
    int wave = t >> 6, lane = t & 63;
    int i = lane & 15, q = lane >> 4;
    int eb = blockIdx.x * 64 + wave * 16;

    short8 afr[2];
    {
        const float* ap = ea + (size_t)(eb + i) * 64 + q * 8;
#pragma unroll
        for (int kt = 0; kt < 2; kt++) {
            float4 x0 = *(const float4*)(ap + kt * 32);
            float4 x1 = *(const float4*)(ap + kt * 32 + 4);
            short8 a;
            a[0] = f2bf(x0.x); a[1] = f2bf(x0.y); a[2] = f2bf(x0.z); a[3] = f2bf(x0.w);
            a[4] = f2bf(x1.x); a[5] = f2bf(x1.y); a[6] = f2bf(x1.z); a[7] = f2bf(x1.w);
            afr[kt] = a;
        }
    }
    int sI[4];
    ushort8v gs[4][2], gt[4][2];
#pragma unroll
    for (int r = 0; r < 4; r++) {
        int e = eb + q * 4 + r;
        sI[r] = src[e];
        int tg = tgt[e];
        const unsigned short* ps = nodeAxaT + (size_t)sI[r] * 256 + i * 16;
        const unsigned short* pt = nodeAxaT + (size_t)tg * 256 + i * 16;
        gs[r][0] = *(const ushort8v*)(ps);
        gs[r][1] = *(const ushort8v*)(ps + 8);
        gt[r][0] = *(const ushort8v*)(pt);
        gt[r][1] = *(const ushort8v*)(pt + 8);
    }
    float part[4][4];
#pragma unroll
    for (int h = 0; h < 4; h++)
#pragma unroll
        for (int r = 0; r < 4; r++) part[h][r] = 0.f;

#pragma unroll
    for (int nt = 0; nt < 16; nt++) {
        const short* wrow = ldsW + (nt * 16 + i) * 72 + q * 8;
        short8 b0 = *(const short8*)(wrow);
        short8 b1 = *(const short8*)(wrow + 32);
        fragC acc = {0.f, 0.f, 0.f, 0.f};
        acc = __builtin_amdgcn_mfma_f32_16x16x32_bf16(afr[0], b0, acc, 0, 0, 0);
        acc = __builtin_amdgcn_mfma_f32_16x16x32_bf16(afr[1], b1, acc, 0, 0, 0);
        float atti = attS[nt * 16 + i];
        float attj = attS[256 + nt * 16 + i];
        int h = nt >> 2;
#pragma unroll
        for (int r = 0; r < 4; r++) {
            float P = acc[r];
            float oi = softplus_f(bf2f(gs[r][nt >> 3][nt & 7]) + P);
            float oj = softplus_f(bf2f(gt[r][nt >> 3][nt & 7]) + P);
            part[h][r] += oi * atti + oj * attj;
        }
    }
    const float inv_s = 0.99999500003749968f;
#pragma unroll
    for (int r = 0; r < 4; r++) {
        float pr[4];
#pragma unroll
        for (int h = 0; h < 4; h++) {
            float p = part[h][r];
            p += __shfl_xor(p, 1);
            p += __shfl_xor(p, 2);
            p += __shfl_xor(p, 4);
            p += __shfl_xor(p, 8);
            pr[h] = p;
        }
        if (i == 0) {
            float av[4];
#pragma unroll
            for (int h = 0; h < 4; h++) {
                float araw = softplus_f(pr[h]);
                av[h] = __expf(softplus_f(araw * inv_s * gamma[h] + beta[h]));
            }
            int e = eb + q * 4 + r;
            *(float4*)(alphaBuf + (size_t)e * 4) = make_float4(av[0], av[1], av[2], av[3]);
            atomicAdd(&segSum[sI[r] * 4 + 0], av[0]);
            atomicAdd(&segSum[sI[r] * 4 + 1], av[1]);
            atomicAdd(&segSum[sI[r] * 4 + 2], av[2]);
            atomicAdd(&segSum[sI[r] * 4 + 3], av[3]);
        }
    }
}

// ---------- K3: pw branch, ea@Wa2 + z1, combine, scatter ----------
// LDS = 32,768 B exactly (5 blocks/CU): stride-64 rows with XOR-chunk swizzle
// (16B chunk c of row t stored at chunk c^(t&7)) — conflict-optimal without pad.
// pw*gate transpose reuses the region BEFORE WaTb is staged. VGPR capped via
// __launch_bounds__(256,5); ga gathered in halves; rij read deferred to epilogue.
__global__ __launch_bounds__(256, 5) void k_final(
    const float* __restrict__ ea, const float* __restrict__ pw,
    const float* __restrict__ rij,
    const int* __restrict__ src, const int* __restrict__ tgt,
    const unsigned short* __restrict__ nodeAxaT, const unsigned short* __restrict__ nodeGT,
    const float* __restrict__ nodeDT,
    const short* __restrict__ WaTb, const short* __restrict__ W2gTb,
    const short* __restrict__ W2Tb,
    const float* __restrict__ alphaBuf, const float* __restrict__ segSum,
    float* __restrict__ out) {
    __shared__ short ldsW[256 * 64];   // 32,768 B, XOR-chunk swizzled
    int t = threadIdx.x;
    int wave = t >> 6, lane = t & 63;
    int i = lane & 15, q = lane >> 4;
    int swz = i & 7;
    int eb = blockIdx.x * 64 + wave * 16;

    int sI[4], tgI[4];
    float wal[4][4];
#pragma unroll
    for (int r = 0; r < 4; r++) {
        int e = eb + q * 4 + r;
        sI[r] = src[e];
        tgI[r] = tgt[e];
        float4 av = *(const float4*)(alphaBuf + (size_t)e * 4);
        float4 sv = *(const float4*)(segSum + (size_t)sI[r] * 4);
        wal[r][0] = av.x / (sv.x + 1e-16f) * 0.25f;
        wal[r][1] = av.y / (sv.y + 1e-16f) * 0.25f;
        wal[r][2] = av.z / (sv.z + 1e-16f) * 0.25f;
        wal[r][3] = av.w / (sv.w + 1e-16f) * 0.25f;
    }

    // ---- pw gate GEMM; transposed+swizzled write into this wave's LDS region ----
    short* wreg = ldsW + wave * 16 * 64;   // 16 rows of 64 shorts
    {
        short8 pfr[2];
        const float* pp = pw + (size_t)(eb + i) * 64 + q * 8;
#pragma unroll
        for (int kt = 0; kt < 2; kt++) {
            float4 x0 = *(const float4*)(pp + kt * 32);
            float4 x1 = *(const float4*)(pp + kt * 32 + 4);
            short8 a;
            a[0] = f2bf(x0.x); a[1] = f2bf(x0.y); a[2] = f2bf(x0.z); a[3] = f2bf(x0.w);
            a[4] = f2bf(x1.x); a[5] = f2bf(x1.y); a[6] = f2bf(x1.z); a[7] = f2bf(x1.w);
            pfr[kt] = a;
        }
#pragma unroll
        for (int nt = 0; nt < 4; nt++) {
            const short* wrow = W2gTb + (nt * 16 + i) * 64 + q * 8;
            short8 b0 = *(const short8*)(wrow);
            short8 b1 = *(const short8*)(wrow + 32);
            fragC g = {0.f, 0.f, 0.f, 0.f};
            g = __builtin_amdgcn_mfma_f32_16x16x32_bf16(pfr[0], b0, g, 0, 0, 0);
            g = __builtin_amdgcn_mfma_f32_16x16x32_bf16(pfr[1], b1, g, 0, 0, 0);
            int k = nt * 16 + i;
            int ck = k >> 3, wk = k & 7;
#pragma unroll
            for (int r = 0; r < 4; r++) {
                float pv = pw[(size_t)(eb + q * 4 + r) * 64 + k];
                int rr = q * 4 + r;
                wreg[rr * 64 + ((ck ^ (rr & 7)) << 3) + wk] = f2bf(pv * sigmoid_f(g[r]));
            }
        }
    }

    // ---- a2 fragment from own wave region (wave-private; compiler orders ds ops) ----
    short8 a2[2];
    {
        const short* arow = wreg + i * 64;
        a2[0] = *(const short8*)(arow + ((q ^ swz) << 3));
        a2[1] = *(const short8*)(arow + (((q + 4) ^ swz) << 3));
    }
    __syncthreads();   // all waves done reading their pw*gate transpose

    // ---- stage WaTb into ldsW (swizzled) ----
    {
        const float4* s4 = (const float4*)(WaTb + t * 64);
#pragma unroll
        for (int c = 0; c < 8; c++)
            *(float4*)(ldsW + t * 64 + (((c ^ (t & 7)) << 3))) = s4[c];
    }
    __syncthreads();   // WaTb staged and visible

    // ---- ea@Wa2 + z1 ----
    short8 afr[2];
    {
        const float* ap = ea + (size_t)(eb + i) * 64 + q * 8;
#pragma unroll
        for (int kt = 0; kt < 2; kt++) {
            float4 x0 = *(const float4*)(ap + kt * 32);
            float4 x1 = *(const float4*)(ap + kt * 32 + 4);
            short8 a;
            a[0] = f2bf(x0.x); a[1] = f2bf(x0.y); a[2] = f2bf(x0.z); a[3] = f2bf(x0.w);
            a[4] = f2bf(x1.x); a[5] = f2bf(x1.y); a[6] = f2bf(x1.z); a[7] = f2bf(x1.w);
            afr[kt] = a;
        }
    }
    float z1[4][4];
#pragma unroll
    for (int j = 0; j < 4; j++)
#pragma unroll
        for (int r = 0; r < 4; r++) z1[j][r] = 0.f;
#pragma unroll
    for (int half = 0; half < 2; half++) {
        ushort8v ga[4];
#pragma unroll
        for (int r = 0; r < 4; r++)
            ga[r] = *(const ushort8v*)(nodeAxaT + (size_t)tgI[r] * 256 + i * 16 + half * 8);
#pragma unroll
        for (int nn = 0; nn < 8; nn++) {
            int nt = half * 8 + nn;
            const short* wr = ldsW + (nt * 16 + i) * 64;
            short8 b0 = *(const short8*)(wr + ((q ^ swz) << 3));
            short8 b1 = *(const short8*)(wr + (((q + 4) ^ swz) << 3));
            fragC acc = {0.f, 0.f, 0.f, 0.f};
            acc = __builtin_amdgcn_mfma_f32_16x16x32_bf16(afr[0], b0, acc, 0, 0, 0);
            acc = __builtin_amdgcn_mfma_f32_16x16x32_bf16(afr[1], b1, acc, 0, 0, 0);
            int h = nt >> 2, j = nt & 3;
#pragma unroll
            for (int r = 0; r < 4; r++) {
                float oj = softplus_f(bf2f(ga[r][nn]) + acc[r]);
                z1[j][r] += oj * wal[r][h];
            }
        }
    }

    // ---- z2 GEMM on top of z1 (MFMA C-operand) ----
    fragC zt[4];
#pragma unroll
    for (int nt = 0; nt < 4; nt++) {
        const short* wrow = W2Tb + (nt * 16 + i) * 64 + q * 8;
        short8 b0 = *(const short8*)(wrow);
        short8 b1 = *(const short8*)(wrow + 32);
        fragC z = {z1[nt][0], z1[nt][1], z1[nt][2], z1[nt][3]};
        z = __builtin_amdgcn_mfma_f32_16x16x32_bf16(a2[0], b0, z, 0, 0, 0);
        z = __builtin_amdgcn_mfma_f32_16x16x32_bf16(a2[1], b1, z, 0, 0, 0);
        zt[nt] = z;
    }

    // ---- epilogue per edge ----
#pragma unroll
    for (int r = 0; r < 4; r++) {
        float rr = rij[eb + q * 4 + r];
        if (rr == 0.f) rr = 1e-8f;
        float ir = 1.f / rr;
        const unsigned short* Gs = nodeGT + (size_t)sI[r] * 256;
        const unsigned short* Gt = nodeGT + (size_t)tgI[r] * 256;
        const float* Ds = nodeDT + (size_t)sI[r] * 128;
        const float* Dt = nodeDT + (size_t)tgI[r] * 128;
        ushort4v ag1 = *(const ushort4v*)(Gs + i * 4);
        ushort4v am1 = *(const ushort4v*)(Gs + 128 + i * 4);
        ushort4v ag2 = *(const ushort4v*)(Gt + 64 + i * 4);
        ushort4v am2 = *(const ushort4v*)(Gt + 192 + i * 4);
        float4 ag3s = *(const float4*)(Ds + i * 4);
        float4 am3s = *(const float4*)(Ds + 64 + i * 4);
        float4 ag3t = *(const float4*)(Dt + i * 4);
        float4 am3t = *(const float4*)(Dt + 64 + i * 4);
        float g3s[4] = {ag3s.x, ag3s.y, ag3s.z, ag3s.w};
        float m3s[4] = {am3s.x, am3s.y, am3s.z, am3s.w};
        float g3t[4] = {ag3t.x, ag3t.y, ag3t.z, ag3t.w};
        float m3t[4] = {am3t.x, am3t.y, am3t.z, am3t.w};
#pragma unroll
        for (int j = 0; j < 4; j++) {
            int d = j * 16 + i;
            float gl = bf2f(ag1[j]) + bf2f(ag2[j]) + (g3s[j] - g3t[j]) * ir;
            float ml = bf2f(am1[j]) + bf2f(am2[j]) + (m3s[j] - m3t[j]) * ir;
            float eg = sigmoid_f(gl);
            float em = ml > 0.f ? ml : (__expf(ml) - 1.f);
            float z = eg * em * (zt[j][r]);
            atomicAdd(&out[(size_t)sI[r] * 64 + d], z);
        }
    }
}

extern "C" void kernel_launch(void* const* d_in, const int* in_sizes, int n_in,
                              void* d_out, int out_size, void* d_ws, size_t ws_size,
                              hipStream_t stream) {
    const float* input = (const float*)d_in[0];
    const float* rij   = (const float*)d_in[1];
    const float* pw    = (const float*)d_in[2];
    const float* ea    = (const float*)d_in[3];
    const float* Wg    = (const float*)d_in[4];
    const float* Wm    = (const float*)d_in[5];
    const float* W2    = (const float*)d_in[6];
    const float* W2g   = (const float*)d_in[7];
    const float* Wa    = (const float*)d_in[8];
    const float* att   = (const float*)d_in[9];
    const float* gamma = (const float*)d_in[10];
    const float* beta  = (const float*)d_in[11];
    const int* srcIdx  = (const int*)d_in[12];
    const int* tgtIdx  = (const int*)d_in[13];
    float* out = (float*)d_out;

    char* wsb = (char*)d_ws;
    short* nodeAxaT = (short*)(wsb);                      // 20,480,000
    short* nodeGT   = (short*)(wsb + 20480000);           // 20,480,000
    float* nodeDT   = (float*)(wsb + 40960000);           // 20,480,000
    float* alphaBuf = (float*)(wsb + 61440000);           // 10,240,000
    float* segSum   = (float*)(wsb + 71680000);           // 640,000
    short* WaTb     = (short*)(wsb + 72320000);           // 32,768
    short* W2gTb    = (short*)(wsb + 72352768);           // 8,192
    short* W2Tb     = (short*)(wsb + 72360960);           // 8,192

    hipMemsetAsync(wsb + 71680000, 0, 640000, stream);    // segSum = 0
    hipMemcpyAsync(d_out, (const void*)input, (size_t)N_NODES * 64 * sizeof(float),
                   hipMemcpyDeviceToDevice, stream);

    k_weights<<<32, 256, 0, stream>>>(Wa, W2g, W2, WaTb, W2gTb, W2Tb);
    k_node_pre<<<N_NODES / NT0, 256, 0, stream>>>(input, Wg, Wm, Wa,
                                                  nodeAxaT, nodeGT, nodeDT);
    k_alpha<<<N_EDGES / 64, 256, 0, stream>>>(ea, srcIdx, tgtIdx,
                                              (const unsigned short*)nodeAxaT, WaTb,
                                              att, gamma, beta, alphaBuf, segSum);
    k_final<<<N_EDGES / 64, 256, 0, stream>>>(ea, pw, rij, srcIdx, tgtIdx,
                                              (const unsigned short*)nodeAxaT,
                                              (const unsigned short*)nodeGT, nodeDT,
                                              WaTb, W2gTb, W2Tb, alphaBuf, segSum, out);
}

// Round 6
// 953.155 us; speedup vs baseline: 1.2936x; 1.2936x over previous
//
#include <hip/hip_runtime.h>
#include <math.h>

#define N_NODES 40000
#define N_EDGES 640000
#define NT0 16

typedef short short8 __attribute__((ext_vector_type(8)));
typedef unsigned short ushort8v __attribute__((ext_vector_type(8)));
typedef unsigned short ushort4v __attribute__((ext_vector_type(4)));
typedef float fragC __attribute__((ext_vector_type(4)));

__device__ __forceinline__ float softplus_f(float x) {
    return x > 15.f ? x : __logf(1.f + __expf(x));
}
__device__ __forceinline__ float sigmoid_f(float x) {
    return 1.f / (1.f + __expf(-x));
}
__device__ __forceinline__ short f2bf(float f) {
    unsigned u = __float_as_uint(f);
    u += 0x7FFF + ((u >> 16) & 1);   // round-to-nearest-even
    return (short)(u >> 16);
}
__device__ __forceinline__ float bf2f(unsigned short u) {
    return __uint_as_float(((unsigned)u) << 16);
}

// ---------- bf16 weight prep ----------
__global__ void k_weights(const float* __restrict__ Wa, const float* __restrict__ W2g,
                          const float* __restrict__ W2, short* __restrict__ WaTb,
                          short* __restrict__ W2gTb, short* __restrict__ W2Tb) {
    int idx = blockIdx.x * blockDim.x + threadIdx.x;
    int stride = gridDim.x * blockDim.x;
    for (int i = idx; i < 256 * 64; i += stride) {
        int c = i >> 6, k = i & 63;
        WaTb[i] = f2bf(Wa[(64 + k) * 256 + c]);
    }
    for (int i = idx; i < 64 * 64; i += stride) {
        int c = i >> 6, k = i & 63;
        W2gTb[i] = f2bf(W2g[k * 64 + c]);
        W2Tb[i]  = f2bf(W2[k * 64 + c]);
    }
}

// ---------- K0: node precompute into transposed/packed tables ----------
// nodeAxaT (bf16): [n][ (co&15)*16 + (co>>4) ]  co = col of input@Wa_nodehalf (0..255)
// nodeGD   (bf16): [n][ Ag1 | Am1 | Ag2 | Am2 | G3 | M3 ] offsets 0/128/64/192/256/320,
//                  each 64, idx (d&15)*4 + (d>>4). One 768B row replaces GT+DT(fp32):
//                  halves delta-term gather bytes, 12->8 cache lines per edge-side.
__global__ __launch_bounds__(256) void k_node_pre(const float* __restrict__ X,
                                                  const float* __restrict__ Wg,
                                                  const float* __restrict__ Wm,
                                                  const float* __restrict__ Wa,
                                                  short* __restrict__ nodeAxaT,
                                                  short* __restrict__ nodeGD) {
    __shared__ float xs[NT0 * 64];
    int t = threadIdx.x;
    int n0 = blockIdx.x * NT0;
    ((float4*)xs)[t] = ((const float4*)(X + (size_t)n0 * 64))[t];
    __syncthreads();
    for (int c = t; c < 640; c += 256) {
        const float* wptr;
        int ld;
        if (c < 192)      { wptr = Wg + (c >> 6) * 64 * 64 + (c & 63); ld = 64; }
        else if (c < 384) { wptr = Wm + ((c - 192) >> 6) * 64 * 64 + (c & 63); ld = 64; }
        else              { wptr = Wa + (c - 384); ld = 256; }
        float acc[NT0];
#pragma unroll
        for (int n = 0; n < NT0; n++) acc[n] = 0.f;
        for (int kc = 0; kc < 16; kc++) {
            float w0 = wptr[(4 * kc + 0) * ld];
            float w1 = wptr[(4 * kc + 1) * ld];
            float w2 = wptr[(4 * kc + 2) * ld];
            float w3 = wptr[(4 * kc + 3) * ld];
#pragma unroll
            for (int n = 0; n < NT0; n++) {
                float4 x = ((float4*)xs)[n * 16 + kc];
                acc[n] += x.x * w0 + x.y * w1 + x.z * w2 + x.w * w3;
            }
        }
#pragma unroll
        for (int n = 0; n < NT0; n++) {
            float v = acc[n];
            size_t nn = (size_t)(n0 + n);
            if (c < 64) {
                nodeGD[nn * 384 + (c & 15) * 4 + (c >> 4)] = f2bf(v);              // Ag1 @0
            } else if (c < 128) {
                int d = c - 64;  nodeGD[nn * 384 + 64 + (d & 15) * 4 + (d >> 4)] = f2bf(v);   // Ag2 @64
            } else if (c < 192) {
                int d = c - 128; nodeGD[nn * 384 + 256 + (d & 15) * 4 + (d >> 4)] = f2bf(v);  // G3 @256
            } else if (c < 256) {
                int d = c - 192; nodeGD[nn * 384 + 128 + (d & 15) * 4 + (d >> 4)] = f2bf(v);  // Am1 @128
            } else if (c < 320) {
                int d = c - 256; nodeGD[nn * 384 + 192 + (d & 15) * 4 + (d >> 4)] = f2bf(v);  // Am2 @192
            } else if (c < 384) {
                int d = c - 320; nodeGD[nn * 384 + 320 + (d & 15) * 4 + (d >> 4)] = f2bf(v);  // M3 @320
            } else {
                int co = c - 384; nodeAxaT[nn * 256 + (co & 15) * 16 + (co >> 4)] = f2bf(v);  // Axa
            }
        }
    }
}

// ---------- K1: MFMA ea@Wa2, alpha, segment sum (Round-4 proven form) ----------
__global__ __launch_bounds__(256) void k_alpha(
    const float* __restrict__ ea, const int* __restrict__ src, const int* __restrict__ tgt,
    const unsigned short* __restrict__ nodeAxaT, const short* __restrict__ WaTb,
    const float* __restrict__ att, const float* __restrict__ gamma,
    const float* __restrict__ beta,
    float* __restrict__ alphaBuf, float* __restrict__ segSum) {
    __shared__ short ldsW[256 * 72];   // padded row stride 72 shorts (144B)
    __shared__ float attS[512];
    int t = threadIdx.x;
    {
        const float4* s4 = (const float4*)(WaTb + t * 64);
        float4* d4 = (float4*)(ldsW + t * 72);
#pragma unroll
        for (int k = 0; k < 8; k++) d4[k] = s4[k];
        attS[t] = att[(t >> 6) * 128 + (t & 63)];
        attS[256 + t] = att[(t >> 6) * 128 + 64 + (t & 63)];
    }
    __syncthreads();
    int wave = t >> 6, lane = t & 63;
    int i = lane & 15, q = lane >> 4;
    int eb = blockIdx.x * 64 + wave * 16;

    short8 afr[2];
    {
        const float* ap = ea + (size_t)(eb + i) * 64 + q * 8;
#pragma unroll
        for (int kt = 0; kt < 2; kt++) {
            float4 x0 = *(const float4*)(ap + kt * 32);
            float4 x1 = *(const float4*)(ap + kt * 32 + 4);
            short8 a;
            a[0] = f2bf(x0.x); a[1] = f2bf(x0.y); a[2] = f2bf(x0.z); a[3] = f2bf(x0.w);
            a[4] = f2bf(x1.x); a[5] = f2bf(x1.y); a[6] = f2bf(x1.z); a[7] = f2bf(x1.w);
            afr[kt] = a;
        }
    }
    int sI[4];
    ushort8v gs[4][2], gt[4][2];
#pragma unroll
    for (int r = 0; r < 4; r++) {
        int e = eb + q * 4 + r;
        sI[r] = src[e];
        int tg = tgt[e];
        const unsigned short* ps = nodeAxaT + (size_t)sI[r] * 256 + i * 16;
        const unsigned short* pt = nodeAxaT + (size_t)tg * 256 + i * 16;
        gs[r][0] = *(const ushort8v*)(ps);
        gs[r][1] = *(const ushort8v*)(ps + 8);
        gt[r][0] = *(const ushort8v*)(pt);
        gt[r][1] = *(const ushort8v*)(pt + 8);
    }
    float part[4][4];
#pragma unroll
    for (int h = 0; h < 4; h++)
#pragma unroll
        for (int r = 0; r < 4; r++) part[h][r] = 0.f;

#pragma unroll
    for (int nt = 0; nt < 16; nt++) {
        const short* wrow = ldsW + (nt * 16 + i) * 72 + q * 8;
        short8 b0 = *(const short8*)(wrow);
        short8 b1 = *(const short8*)(wrow + 32);
        fragC acc = {0.f, 0.f, 0.f, 0.f};
        acc = __builtin_amdgcn_mfma_f32_16x16x32_bf16(afr[0], b0, acc, 0, 0, 0);
        acc = __builtin_amdgcn_mfma_f32_16x16x32_bf16(afr[1], b1, acc, 0, 0, 0);
        float atti = attS[nt * 16 + i];
        float attj = attS[256 + nt * 16 + i];
        int h = nt >> 2;
#pragma unroll
        for (int r = 0; r < 4; r++) {
            float P = acc[r];
            float oi = softplus_f(bf2f(gs[r][nt >> 3][nt & 7]) + P);
            float oj = softplus_f(bf2f(gt[r][nt >> 3][nt & 7]) + P);
            part[h][r] += oi * atti + oj * attj;
        }
    }
    const float inv_s = 0.99999500003749968f;
#pragma unroll
    for (int r = 0; r < 4; r++) {
        float pr[4];
#pragma unroll
        for (int h = 0; h < 4; h++) {
            float p = part[h][r];
            p += __shfl_xor(p, 1);
            p += __shfl_xor(p, 2);
            p += __shfl_xor(p, 4);
            p += __shfl_xor(p, 8);
            pr[h] = p;
        }
        if (i == 0) {
            float av[4];
#pragma unroll
            for (int h = 0; h < 4; h++) {
                float araw = softplus_f(pr[h]);
                av[h] = __expf(softplus_f(araw * inv_s * gamma[h] + beta[h]));
            }
            int e = eb + q * 4 + r;
            *(float4*)(alphaBuf + (size_t)e * 4) = make_float4(av[0], av[1], av[2], av[3]);
            atomicAdd(&segSum[sI[r] * 4 + 0], av[0]);
            atomicAdd(&segSum[sI[r] * 4 + 1], av[1]);
            atomicAdd(&segSum[sI[r] * 4 + 2], av[2]);
            atomicAdd(&segSum[sI[r] * 4 + 3], av[3]);
        }
    }
}

// ---------- K3: pw branch, ea@Wa2 + z1, combine, scatter (Round-4 proven form,
// epilogue switched to the merged bf16 nodeGD table; NO launch-bounds cap —
// capping to 5 waves/EU spilled ~700MB to scratch and regressed 346->621us) ----------
__global__ __launch_bounds__(256) void k_final(
    const float* __restrict__ ea, const float* __restrict__ pw,
    const float* __restrict__ rij,
    const int* __restrict__ src, const int* __restrict__ tgt,
    const unsigned short* __restrict__ nodeAxaT, const unsigned short* __restrict__ nodeGD,
    const short* __restrict__ WaTb, const short* __restrict__ W2gTb,
    const short* __restrict__ W2Tb,
    const float* __restrict__ alphaBuf, const float* __restrict__ segSum,
    float* __restrict__ out) {
    __shared__ short ldsW[256 * 72];   // 36,864 B; WaTb during z1, then pw*gate
    int t = threadIdx.x;
    {
        const float4* s4 = (const float4*)(WaTb + t * 64);
        float4* d4 = (float4*)(ldsW + t * 72);
#pragma unroll
        for (int k = 0; k < 8; k++) d4[k] = s4[k];
    }
    int wave = t >> 6, lane = t & 63;
    int i = lane & 15, q = lane >> 4;
    int eb = blockIdx.x * 64 + wave * 16;

    int sI[4], tgI[4];
    float ir[4];
    float wal[4][4];
#pragma unroll
    for (int r = 0; r < 4; r++) {
        int e = eb + q * 4 + r;
        sI[r] = src[e];
        tgI[r] = tgt[e];
        float rr = rij[e];
        if (rr == 0.f) rr = 1e-8f;
        ir[r] = 1.f / rr;
        float4 av = *(const float4*)(alphaBuf + (size_t)e * 4);
        float4 sv = *(const float4*)(segSum + (size_t)sI[r] * 4);
        wal[r][0] = av.x / (sv.x + 1e-16f) * 0.25f;
        wal[r][1] = av.y / (sv.y + 1e-16f) * 0.25f;
        wal[r][2] = av.z / (sv.z + 1e-16f) * 0.25f;
        wal[r][3] = av.w / (sv.w + 1e-16f) * 0.25f;
    }

    // ---- pw gate GEMM: results kept in registers until after z1 ----
    short pg[4][4];
    {
        short8 pfr[2];
        const float* pp = pw + (size_t)(eb + i) * 64 + q * 8;
#pragma unroll
        for (int kt = 0; kt < 2; kt++) {
            float4 x0 = *(const float4*)(pp + kt * 32);
            float4 x1 = *(const float4*)(pp + kt * 32 + 4);
            short8 a;
            a[0] = f2bf(x0.x); a[1] = f2bf(x0.y); a[2] = f2bf(x0.z); a[3] = f2bf(x0.w);
            a[4] = f2bf(x1.x); a[5] = f2bf(x1.y); a[6] = f2bf(x1.z); a[7] = f2bf(x1.w);
            pfr[kt] = a;
        }
#pragma unroll
        for (int nt = 0; nt < 4; nt++) {
            const short* wrow = W2gTb + (nt * 16 + i) * 64 + q * 8;
            short8 b0 = *(const short8*)(wrow);
            short8 b1 = *(const short8*)(wrow + 32);
            fragC g = {0.f, 0.f, 0.f, 0.f};
            g = __builtin_amdgcn_mfma_f32_16x16x32_bf16(pfr[0], b0, g, 0, 0, 0);
            g = __builtin_amdgcn_mfma_f32_16x16x32_bf16(pfr[1], b1, g, 0, 0, 0);
            int k = nt * 16 + i;
#pragma unroll
            for (int r = 0; r < 4; r++) {
                float pv = pw[(size_t)(eb + q * 4 + r) * 64 + k];
                pg[nt][r] = f2bf(pv * sigmoid_f(g[r]));
            }
        }
    }

    // target Axa rows for z1
    ushort8v ga[4][2];
#pragma unroll
    for (int r = 0; r < 4; r++) {
        const unsigned short* pt = nodeAxaT + (size_t)tgI[r] * 256 + i * 16;
        ga[r][0] = *(const ushort8v*)(pt);
        ga[r][1] = *(const ushort8v*)(pt + 8);
    }

    __syncthreads();   // ldsW (WaTb) staged and visible

    // ---- ea@Wa2 + z1 ----
    short8 afr[2];
    {
        const float* ap = ea + (size_t)(eb + i) * 64 + q * 8;
#pragma unroll
        for (int kt = 0; kt < 2; kt++) {
            float4 x0 = *(const float4*)(ap + kt * 32);
            float4 x1 = *(const float4*)(ap + kt * 32 + 4);
            short8 a;
            a[0] = f2bf(x0.x); a[1] = f2bf(x0.y); a[2] = f2bf(x0.z); a[3] = f2bf(x0.w);
            a[4] = f2bf(x1.x); a[5] = f2bf(x1.y); a[6] = f2bf(x1.z); a[7] = f2bf(x1.w);
            afr[kt] = a;
        }
    }
    float z1[4][4];
#pragma unroll
    for (int j = 0; j < 4; j++)
#pragma unroll
        for (int r = 0; r < 4; r++) z1[j][r] = 0.f;
#pragma unroll
    for (int nt = 0; nt < 16; nt++) {
        const short* wrow = ldsW + (nt * 16 + i) * 72 + q * 8;
        short8 b0 = *(const short8*)(wrow);
        short8 b1 = *(const short8*)(wrow + 32);
        fragC acc = {0.f, 0.f, 0.f, 0.f};
        acc = __builtin_amdgcn_mfma_f32_16x16x32_bf16(afr[0], b0, acc, 0, 0, 0);
        acc = __builtin_amdgcn_mfma_f32_16x16x32_bf16(afr[1], b1, acc, 0, 0, 0);
        int h = nt >> 2, j = nt & 3;
#pragma unroll
        for (int r = 0; r < 4; r++) {
            float oj = softplus_f(bf2f(ga[r][nt >> 3][nt & 7]) + acc[r]);
            z1[j][r] += oj * wal[r][h];
        }
    }

    __syncthreads();   // all waves done reading WaTb from ldsW

    // ---- write pw*gate into the (now free) ldsW wave region ----
    {
        short* pwgW = ldsW + wave * (16 * 72);
#pragma unroll
        for (int nt = 0; nt < 4; nt++)
#pragma unroll
            for (int r = 0; r < 4; r++)
                pwgW[(q * 4 + r) * 72 + nt * 16 + i] = pg[nt][r];
    }
    __syncthreads();   // transpose visible

    // ---- z2 GEMM, accumulating directly on top of z1 (MFMA C-operand) ----
    short8 a2[2];
    {
        const short* prow = ldsW + wave * (16 * 72) + i * 72 + q * 8;
        a2[0] = *(const short8*)(prow);
        a2[1] = *(const short8*)(prow + 32);
    }
    fragC zt[4];
#pragma unroll
    for (int nt = 0; nt < 4; nt++) {
        const short* wrow = W2Tb + (nt * 16 + i) * 64 + q * 8;
        short8 b0 = *(const short8*)(wrow);
        short8 b1 = *(const short8*)(wrow + 32);
        fragC z = {z1[nt][0], z1[nt][1], z1[nt][2], z1[nt][3]};
        z = __builtin_amdgcn_mfma_f32_16x16x32_bf16(a2[0], b0, z, 0, 0, 0);
        z = __builtin_amdgcn_mfma_f32_16x16x32_bf16(a2[1], b1, z, 0, 0, 0);
        zt[nt] = z;
    }

    // ---- epilogue per edge (merged bf16 nodeGD: 4x8B loads per side, one row) ----
#pragma unroll
    for (int r = 0; r < 4; r++) {
        const unsigned short* Gs = nodeGD + (size_t)sI[r] * 384;
        const unsigned short* Gt = nodeGD + (size_t)tgI[r] * 384;
        ushort4v ag1 = *(const ushort4v*)(Gs + i * 4);
        ushort4v am1 = *(const ushort4v*)(Gs + 128 + i * 4);
        ushort4v g3s = *(const ushort4v*)(Gs + 256 + i * 4);
        ushort4v m3s = *(const ushort4v*)(Gs + 320 + i * 4);
        ushort4v ag2 = *(const ushort4v*)(Gt + 64 + i * 4);
        ushort4v am2 = *(const ushort4v*)(Gt + 192 + i * 4);
        ushort4v g3t = *(const ushort4v*)(Gt + 256 + i * 4);
        ushort4v m3t = *(const ushort4v*)(Gt + 320 + i * 4);
#pragma unroll
        for (int j = 0; j < 4; j++) {
            int d = j * 16 + i;
            float gl = bf2f(ag1[j]) + bf2f(ag2[j]) + (bf2f(g3s[j]) - bf2f(g3t[j])) * ir[r];
            float ml = bf2f(am1[j]) + bf2f(am2[j]) + (bf2f(m3s[j]) - bf2f(m3t[j])) * ir[r];
            float eg = sigmoid_f(gl);
            float em = ml > 0.f ? ml : (__expf(ml) - 1.f);
            float z = eg * em * (zt[j][r]);
            atomicAdd(&out[(size_t)sI[r] * 64 + d], z);
        }
    }
}

extern "C" void kernel_launch(void* const* d_in, const int* in_sizes, int n_in,
                              void* d_out, int out_size, void* d_ws, size_t ws_size,
                              hipStream_t stream) {
    const float* input = (const float*)d_in[0];
    const float* rij   = (const float*)d_in[1];
    const float* pw    = (const float*)d_in[2];
    const float* ea    = (const float*)d_in[3];
    const float* Wg    = (const float*)d_in[4];
    const float* Wm    = (const float*)d_in[5];
    const float* W2    = (const float*)d_in[6];
    const float* W2g   = (const float*)d_in[7];
    const float* Wa    = (const float*)d_in[8];
    const float* att   = (const float*)d_in[9];
    const float* gamma = (const float*)d_in[10];
    const float* beta  = (const float*)d_in[11];
    const int* srcIdx  = (const int*)d_in[12];
    const int* tgtIdx  = (const int*)d_in[13];
    float* out = (float*)d_out;

    char* wsb = (char*)d_ws;
    short* nodeAxaT = (short*)(wsb);                      // 20,480,000
    short* nodeGD   = (short*)(wsb + 20480000);           // 30,720,000
    float* alphaBuf = (float*)(wsb + 51200000);           // 10,240,000
    float* segSum   = (float*)(wsb + 61440000);           //    640,000
    short* WaTb     = (short*)(wsb + 62080000);           //     32,768
    short* W2gTb    = (short*)(wsb + 62112768);           //      8,192
    short* W2Tb     = (short*)(wsb + 62120960);           //      8,192

    hipMemsetAsync(wsb + 61440000, 0, 640000, stream);    // segSum = 0
    hipMemcpyAsync(d_out, (const void*)input, (size_t)N_NODES * 64 * sizeof(float),
                   hipMemcpyDeviceToDevice, stream);

    k_weights<<<32, 256, 0, stream>>>(Wa, W2g, W2, WaTb, W2gTb, W2Tb);
    k_node_pre<<<N_NODES / NT0, 256, 0, stream>>>(input, Wg, Wm, Wa,
                                                  nodeAxaT, nodeGD);
    k_alpha<<<N_EDGES / 64, 256, 0, stream>>>(ea, srcIdx, tgtIdx,
                                              (const unsigned short*)nodeAxaT, WaTb,
                                              att, gamma, beta, alphaBuf, segSum);
    k_final<<<N_EDGES / 64, 256, 0, stream>>>(ea, pw, rij, srcIdx, tgtIdx,
                                              (const unsigned short*)nodeAxaT,
                                              (const unsigned short*)nodeGD,
                                              WaTb, W2gTb, W2Tb, alphaBuf, segSum, out);
}